// Round 7
// baseline (74144.354 us; speedup 1.0000x reference)
//
#include <hip/hip_runtime.h>
#include <hip/hip_cooperative_groups.h>
#include <stdint.h>

namespace cg = cooperative_groups;

#define STEPS  100
#define NTHR   256
#define MAXBLK 512

// ---------------------------------------------------------------------------
// Threefry2x32 (JAX-exact, 20 rounds)
// ---------------------------------------------------------------------------
__device__ __forceinline__ uint32_t rotl32(uint32_t v, int r) {
  return (v << r) | (v >> (32 - r));
}

__device__ __forceinline__ void tf2x32(uint32_t k0, uint32_t k1,
                                       uint32_t x0, uint32_t x1,
                                       uint32_t& o0, uint32_t& o1) {
  uint32_t ks2 = k0 ^ k1 ^ 0x1BD11BDAu;
  x0 += k0; x1 += k1;
#define RND(r) { x0 += x1; x1 = rotl32(x1, (r)); x1 ^= x0; }
  RND(13) RND(15) RND(26) RND(6)
  x0 += k1;  x1 += ks2 + 1u;
  RND(17) RND(29) RND(16) RND(24)
  x0 += ks2; x1 += k0 + 2u;
  RND(13) RND(15) RND(26) RND(6)
  x0 += k0;  x1 += k1 + 3u;
  RND(17) RND(29) RND(16) RND(24)
  x0 += k1;  x1 += ks2 + 4u;
  RND(13) RND(15) RND(26) RND(6)
  x0 += ks2; x1 += k0 + 5u;
#undef RND
  o0 = x0; o1 = x1;
}

// ---------------------------------------------------------------------------
// Stage helpers — shared verbatim by megakernel and fallback kernels, so both
// paths are bit-identical to the passing R5 arithmetic.
// ---------------------------------------------------------------------------
__device__ __forceinline__ void poisson_elem(int t, const float* __restrict__ x,
                                             uint32_t k0, uint32_t k1,
                                             int8_t* __restrict__ pois) {
  int p = t >> 9, b = t & 511;
  int j = b * 784 + p;                      // JAX element index
  uint32_t o0, o1;
  tf2x32(k0, k1, 0u, (uint32_t)j, o0, o1);
  uint32_t bits = o0 ^ o1;
  float r = __uint_as_float((bits >> 9) | 0x3F800000u) - 1.0f;
  float xv = x[j];
  int8_t sgn = (xv > 0.f) ? (int8_t)1 : ((xv < 0.f) ? (int8_t)-1 : (int8_t)0);
  pois[t] = (fabsf(xv) * 0.5f > r) ? sgn : (int8_t)0;
}

__device__ __forceinline__ void conv1pool1_job(
    int q, int b, const int8_t* __restrict__ pois, const float* __restrict__ w1,
    float* __restrict__ m1, float* __restrict__ m1s,
    uint8_t* __restrict__ sp1) {
  int qy = q / 14, qx = q % 14;
  float acc[4][20];
#pragma unroll
  for (int t = 0; t < 4; ++t)
#pragma unroll
    for (int oc = 0; oc < 20; ++oc) acc[t][oc] = 0.f;
#pragma unroll
  for (int t = 0; t < 4; ++t) {
    int y = 2 * qy + (t >> 1);
    int xx = 2 * qx + (t & 1);
#pragma unroll
    for (int ky = 0; ky < 5; ++ky) {
      int iy = y + ky - 2;
      if (iy < 0 || iy >= 28) continue;     // block-uniform
#pragma unroll
      for (int kx = 0; kx < 5; ++kx) {
        int ix = xx + kx - 2;
        if (ix < 0 || ix >= 28) continue;   // block-uniform
        float v = (float)pois[(iy * 28 + ix) * 512 + b];
#pragma unroll
        for (int oc = 0; oc < 20; ++oc)
          acc[t][oc] += w1[oc * 25 + ky * 5 + kx] * v;
      }
    }
  }
#pragma unroll
  for (int oc = 0; oc < 20; ++oc) {
    float s4[4];
#pragma unroll
    for (int t = 0; t < 4; ++t) {
      int y = 2 * qy + (t >> 1);
      int xx = 2 * qx + (t & 1);
      int idx = (oc * 784 + y * 28 + xx) * 512 + b;
      float m = m1[idx] + acc[t][oc];
      float sp = 0.f;
      if (m > 1.0f) { sp = 1.f; m = 0.f; }
      m1[idx] = m;
      s4[t] = sp;
    }
    float a = 0.25f * (((s4[0] + s4[1]) + s4[2]) + s4[3]);
    int pidx = (oc * 196 + q) * 512 + b;
    float mm = m1s[pidx] + a;
    uint8_t spp = 0;
    if (mm > 0.75f) { spp = 1; mm = 0.f; }
    m1s[pidx] = mm;
    sp1[pidx] = spp;
  }
}

__device__ __forceinline__ void conv2_job(
    int p, int b, const uint8_t* __restrict__ sp1, const float* __restrict__ wT,
    float* __restrict__ m2, uint8_t* __restrict__ s2) {
  int y = p / 14, xx = p % 14;
  float acc[50];
#pragma unroll
  for (int oc = 0; oc < 50; ++oc) acc[oc] = 0.f;
  for (int ic = 0; ic < 20; ++ic) {
#pragma unroll
    for (int ky = 0; ky < 5; ++ky) {
      int iy = y + ky - 2;
      if (iy < 0 || iy >= 14) continue;
#pragma unroll
      for (int kx = 0; kx < 5; ++kx) {
        int ix = xx + kx - 2;
        if (ix < 0 || ix >= 14) continue;
        float v = (float)sp1[(ic * 196 + iy * 14 + ix) * 512 + b];
        const float* wrow = wT + (ic * 25 + ky * 5 + kx) * 50;
#pragma unroll
        for (int oc = 0; oc < 50; ++oc)
          acc[oc] += wrow[oc] * v;
      }
    }
  }
#pragma unroll
  for (int oc = 0; oc < 50; ++oc) {
    int idx = (oc * 196 + p) * 512 + b;
    float m = m2[idx] + acc[oc];
    uint8_t sp = 0;
    if (m > 1.0f) { sp = 1; m = 0.f; }
    m2[idx] = m;
    s2[idx] = sp;
  }
}

__device__ __forceinline__ void pool2_elem(int t, const uint8_t* __restrict__ s2,
                                           float* __restrict__ m2s,
                                           uint8_t* __restrict__ sp2) {
  int b = t & 511;
  int r = t >> 9;
  int c = r / 49, qq = r % 49;
  int yo = qq / 7, xo = qq % 7;
  int ibase = (c * 196 + 2 * yo * 14 + 2 * xo) * 512 + b;
  float s00 = (float)s2[ibase];
  float s01 = (float)s2[ibase + 512];
  float s10 = (float)s2[ibase + 14 * 512];
  float s11 = (float)s2[ibase + 14 * 512 + 512];
  float a = 0.25f * (((s00 + s01) + s10) + s11);
  float m = m2s[t] + a;
  uint8_t sp = 0;
  if (m > 0.75f) { sp = 1; m = 0.f; }
  m2s[t] = m;
  sp2[t] = sp;
}

__device__ __forceinline__ void fc0_job(int n, int b,
                                        const uint8_t* __restrict__ sp2,
                                        const float* __restrict__ wf0,
                                        float* __restrict__ mf0,
                                        float* __restrict__ Tf0) {
  const float* w0 = wf0 + n * 2450;
  float acc = 0.f;
  for (int k0 = 0; k0 < 2450; k0 += 10) {   // 2450 = 245*10, k ascending
    float v[10];
#pragma unroll
    for (int u = 0; u < 10; ++u)
      v[u] = (float)sp2[(k0 + u) * 512 + b];
#pragma unroll
    for (int u = 0; u < 10; ++u)
      acc += w0[k0 + u] * v[u];
  }
  int idx = n * 512 + b;
  float m = mf0[idx] + acc;
  float sp = 0.f;
  if (m > 1.0f) { sp = 1.f; m = 0.f; }
  mf0[idx] = m;
  Tf0[idx] += sp;
}

__device__ __forceinline__ void fc1_elem(int idx, const float* __restrict__ Tf0,
                                         const float* __restrict__ wf1,
                                         float* __restrict__ out) {
  int b = idx / 10, i = idx % 10;
  float a = 0.f;
  for (int j = 0; j < 200; ++j) a += Tf0[j * 512 + b] * wf1[i * 200 + j];
  out[idx] = (a / 1.0f) / 100.0f;
}

// ---------------------------------------------------------------------------
// Cooperative megakernel — grid-stride over all stages, valid for ANY grid.
// ---------------------------------------------------------------------------
__global__ __launch_bounds__(256, 2) void snn_mega(
    const float* __restrict__ x, const float* __restrict__ w1,
    const float* __restrict__ w2, const float* __restrict__ wf0,
    const float* __restrict__ wf1, float* __restrict__ out,
    float* __restrict__ ws) {
  cg::grid_group grid = cg::this_grid();
  const int nb  = gridDim.x;
  const int nt  = nb * NTHR;
  const int tid = blockIdx.x * NTHR + threadIdx.x;

  // workspace layout (matches fallback path exactly)
  float* m1  = ws;                  // [20*784][512]
  float* m1s = m1  + 8028160;       // [20*196][512]
  float* m2  = m1s + 2007040;       // [50*196][512]
  float* m2s = m2  + 5017600;       // [50*49][512]
  float* mf0 = m2s + 1254400;       // [200][512]
  float* Tf0 = mf0 + 102400;        // [200][512]
  float* wT  = Tf0 + 102400;        // [500][50]
  uint32_t* keybuf = (uint32_t*)(wT + 25000);   // 256 u32
  int8_t*  pois = (int8_t*)(keybuf + 256);      // [784][512] bytes
  uint8_t* sp1  = (uint8_t*)(pois + 401408);    // [20*196][512]
  uint8_t* s2   = sp1 + 2007040;                // [50*196][512]
  uint8_t* sp2  = s2  + 5017600;                // [50*49][512]

  // prologue: zero fp32 state (16,512,000 floats), keys, w2 transpose
  {
    float4 z4; z4.x = z4.y = z4.z = z4.w = 0.f;
    float4* wsv = (float4*)ws;
    for (int i = tid; i < 4128000; i += nt) wsv[i] = z4;
    if (tid < STEPS) {
      uint32_t a, b;
      tf2x32(0u, 42u, 0u, (uint32_t)tid, a, b);
      keybuf[2 * tid] = a;
      keybuf[2 * tid + 1] = b;
    }
    for (int i = tid; i < 25000; i += nt) {
      int oc = i / 500, q = i % 500;
      wT[q * 50 + oc] = w2[i];
    }
  }
  grid.sync();

  // poisson for step 0
  {
    uint32_t k0 = keybuf[0], k1 = keybuf[1];
    for (int t = tid; t < 401408; t += nt) poisson_elem(t, x, k0, k1, pois);
  }
  grid.sync();

  for (int s = 0; s < STEPS; ++s) {
    // stage 1: conv1 + fire + pool1 + fire (392 jobs)
    for (int jj = blockIdx.x; jj < 392; jj += nb)
      conv1pool1_job(jj >> 1, ((jj & 1) << 8) + threadIdx.x,
                     pois, w1, m1, m1s, sp1);
    grid.sync();

    // stage 2: conv2 + fire (392 jobs)
    for (int jj = blockIdx.x; jj < 392; jj += nb)
      conv2_job(jj >> 1, ((jj & 1) << 8) + threadIdx.x, sp1, wT, m2, s2);
    grid.sync();

    // stage 3: pool2 + fire
    for (int t = tid; t < 1254400; t += nt) pool2_elem(t, s2, m2s, sp2);
    grid.sync();

    // stage 4: fc0 + fire + Tf0 (400 jobs), overlapped with poisson(s+1)
    for (int jj = blockIdx.x; jj < 400; jj += nb)
      fc0_job(jj >> 1, ((jj & 1) << 8) + threadIdx.x, sp2, wf0, mf0, Tf0);
    if (s + 1 < STEPS) {
      uint32_t k0 = keybuf[2 * (s + 1)], k1 = keybuf[2 * (s + 1) + 1];
      for (int t = tid; t < 401408; t += nt) poisson_elem(t, x, k0, k1, pois);
    }
    grid.sync();
  }

  // epilogue: fc1
  for (int idx = tid; idx < 5120; idx += nt) fc1_elem(idx, Tf0, wf1, out);
}

// ---------------------------------------------------------------------------
// Fallback multi-kernel path (R5-proven structure, same helpers)
// ---------------------------------------------------------------------------
__global__ void keys_k(uint32_t* __restrict__ kb) {
  int i = threadIdx.x;
  if (i < STEPS) {
    uint32_t a, b;
    tf2x32(0u, 42u, 0u, (uint32_t)i, a, b);
    kb[2 * i] = a;
    kb[2 * i + 1] = b;
  }
}
__global__ void wt_k(const float* __restrict__ w2, float* __restrict__ wT) {
  int i = blockIdx.x * blockDim.x + threadIdx.x;
  if (i >= 25000) return;
  int oc = i / 500, q = i % 500;
  wT[q * 50 + oc] = w2[i];
}
__global__ void pois_k(const float* __restrict__ x,
                       const uint32_t* __restrict__ kb, int step,
                       int8_t* __restrict__ pois) {
  int t = blockIdx.x * blockDim.x + threadIdx.x;
  if (t < 401408) poisson_elem(t, x, kb[2 * step], kb[2 * step + 1], pois);
}
__global__ __launch_bounds__(256) void c1_k(
    const int8_t* __restrict__ pois, const float* __restrict__ w1,
    float* __restrict__ m1, float* __restrict__ m1s,
    uint8_t* __restrict__ sp1) {
  conv1pool1_job(blockIdx.x >> 1, ((blockIdx.x & 1) << 8) + threadIdx.x,
                 pois, w1, m1, m1s, sp1);
}
__global__ __launch_bounds__(256) void c2_k(
    const uint8_t* __restrict__ sp1, const float* __restrict__ wT,
    float* __restrict__ m2, uint8_t* __restrict__ s2) {
  conv2_job(blockIdx.x >> 1, ((blockIdx.x & 1) << 8) + threadIdx.x,
            sp1, wT, m2, s2);
}
__global__ void p2_k(const uint8_t* __restrict__ s2, float* __restrict__ m2s,
                     uint8_t* __restrict__ sp2) {
  int t = blockIdx.x * blockDim.x + threadIdx.x;
  if (t < 1254400) pool2_elem(t, s2, m2s, sp2);
}
__global__ __launch_bounds__(256) void fc0_k(
    const uint8_t* __restrict__ sp2, const float* __restrict__ wf0,
    float* __restrict__ mf0, float* __restrict__ Tf0) {
  fc0_job(blockIdx.x >> 1, ((blockIdx.x & 1) << 8) + threadIdx.x,
          sp2, wf0, mf0, Tf0);
}
__global__ void fc1_k(const float* __restrict__ Tf0,
                      const float* __restrict__ wf1,
                      float* __restrict__ out) {
  int idx = blockIdx.x * blockDim.x + threadIdx.x;
  if (idx < 5120) fc1_elem(idx, Tf0, wf1, out);
}

// ---------------------------------------------------------------------------
extern "C" void kernel_launch(void* const* d_in, const int* in_sizes, int n_in,
                              void* d_out, int out_size, void* d_ws, size_t ws_size,
                              hipStream_t stream) {
  (void)in_sizes; (void)n_in; (void)out_size; (void)ws_size;
  const float* x   = (const float*)d_in[0];
  const float* w1  = (const float*)d_in[1];
  const float* w2  = (const float*)d_in[2];
  const float* wf0 = (const float*)d_in[3];
  const float* wf1 = (const float*)d_in[4];
  float* out = (float*)d_out;
  float* ws  = (float*)d_ws;

  // occupancy-clamped cooperative grid (256 CUs on gfx950)
  int occ = 0;
  hipError_t oe = hipOccupancyMaxActiveBlocksPerMultiprocessor(
      &occ, (const void*)snn_mega, NTHR, 0);
  int blocks = (oe == hipSuccess && occ > 0) ? occ * 256 : 0;
  if (blocks > MAXBLK) blocks = MAXBLK;

  bool done = false;
  if (blocks > 0) {
    void* args[] = {(void*)&x, (void*)&w1, (void*)&w2, (void*)&wf0,
                    (void*)&wf1, (void*)&out, (void*)&ws};
    hipError_t e = hipLaunchCooperativeKernel(
        (const void*)snn_mega, dim3(blocks), dim3(NTHR), args, 0, stream);
    if (e == hipSuccess) done = true;
    else (void)hipGetLastError();   // clear sticky error, use fallback
  }

  if (!done) {
    // deterministic fallback: R5-proven multi-kernel path
    float* m1  = ws;
    float* Tf0 = ws + 8028160 + 2007040 + 5017600 + 1254400 + 102400;
    float* wT  = Tf0 + 102400;
    uint32_t* keybuf = (uint32_t*)(wT + 25000);
    int8_t*  pois = (int8_t*)(keybuf + 256);
    uint8_t* sp1  = (uint8_t*)(pois + 401408);
    uint8_t* s2   = sp1 + 2007040;
    uint8_t* sp2  = s2  + 5017600;
    float* m1s = m1  + 8028160;
    float* m2  = m1s + 2007040;
    float* m2s = m2  + 5017600;
    float* mf0 = m2s + 1254400;

    hipMemsetAsync(ws, 0, 16512000 * sizeof(float), stream);
    keys_k<<<1, 128, 0, stream>>>(keybuf);
    wt_k<<<98, 256, 0, stream>>>(w2, wT);
    for (int s = 0; s < STEPS; ++s) {
      pois_k<<<1568, 256, 0, stream>>>(x, keybuf, s, pois);
      c1_k<<<392, 256, 0, stream>>>(pois, w1, m1, m1s, sp1);
      c2_k<<<392, 256, 0, stream>>>(sp1, wT, m2, s2);
      p2_k<<<4900, 256, 0, stream>>>(s2, m2s, sp2);
      fc0_k<<<400, 256, 0, stream>>>(sp2, wf0, mf0, Tf0);
    }
    fc1_k<<<20, 256, 0, stream>>>(Tf0, wf1, out);
  }
}

// Round 8
// 26558.481 us; speedup vs baseline: 2.7917x; 2.7917x over previous
//
#include <hip/hip_runtime.h>
#include <stdint.h>

#define STEPS 100

// ---------------------------------------------------------------------------
// Threefry2x32 (JAX-exact, 20 rounds)
// ---------------------------------------------------------------------------
__device__ __forceinline__ uint32_t rotl32(uint32_t v, int r) {
  return (v << r) | (v >> (32 - r));
}

__device__ __forceinline__ void tf2x32(uint32_t k0, uint32_t k1,
                                       uint32_t x0, uint32_t x1,
                                       uint32_t& o0, uint32_t& o1) {
  uint32_t ks2 = k0 ^ k1 ^ 0x1BD11BDAu;
  x0 += k0; x1 += k1;
#define RND(r) { x0 += x1; x1 = rotl32(x1, (r)); x1 ^= x0; }
  RND(13) RND(15) RND(26) RND(6)
  x0 += k1;  x1 += ks2 + 1u;
  RND(17) RND(29) RND(16) RND(24)
  x0 += ks2; x1 += k0 + 2u;
  RND(13) RND(15) RND(26) RND(6)
  x0 += k0;  x1 += k1 + 3u;
  RND(17) RND(29) RND(16) RND(24)
  x0 += k1;  x1 += ks2 + 4u;
  RND(13) RND(15) RND(26) RND(6)
  x0 += ks2; x1 += k0 + 5u;
#undef RND
  o0 = x0; o1 = x1;
}

__global__ void keys_k(uint32_t* __restrict__ kb) {
  int i = threadIdx.x;
  if (i < STEPS) {
    uint32_t a, b;
    tf2x32(0u, 42u, 0u, (uint32_t)i, a, b);
    kb[2 * i] = a;
    kb[2 * i + 1] = b;
  }
}

__global__ void wt_k(const float* __restrict__ w2, float* __restrict__ wT) {
  int i = blockIdx.x * blockDim.x + threadIdx.x;
  if (i >= 25000) return;
  int oc = i / 500, q = i % 500;
  wT[q * 50 + oc] = w2[i];
}

// ---------------------------------------------------------------------------
// Poisson spikes -> int8 {-1,0,1}, batch-innermost: pois[p*512+b].
// JAX element index j = b*784 + p.
// ---------------------------------------------------------------------------
__global__ void pois_k(const float* __restrict__ x,
                       const uint32_t* __restrict__ kb, int step,
                       int8_t* __restrict__ pois) {
  int t = blockIdx.x * blockDim.x + threadIdx.x;
  if (t >= 401408) return;
  int p = t >> 9, b = t & 511;
  int j = b * 784 + p;
  uint32_t k0 = kb[2 * step], k1 = kb[2 * step + 1];
  uint32_t o0, o1;
  tf2x32(k0, k1, 0u, (uint32_t)j, o0, o1);
  uint32_t bits = o0 ^ o1;
  float r = __uint_as_float((bits >> 9) | 0x3F800000u) - 1.0f;
  float xv = x[j];
  int8_t sgn = (xv > 0.f) ? (int8_t)1 : ((xv < 0.f) ? (int8_t)-1 : (int8_t)0);
  pois[t] = (fabsf(xv) * 0.5f > r) ? sgn : (int8_t)0;
}

// ---------------------------------------------------------------------------
// Fused conv1 (1->20, 5x5, pad 2) + IF fire + 2x2 avgpool + IF fire.
// Block = (pool-quad q, 256-batch half); lane = batch. Bit-identical sums.
// ---------------------------------------------------------------------------
__global__ __launch_bounds__(256) void c1_k(
    const int8_t* __restrict__ pois, const float* __restrict__ w1,
    float* __restrict__ m1, float* __restrict__ m1s,
    uint8_t* __restrict__ sp1) {
  int q = blockIdx.x >> 1;                 // 0..195
  int b = ((blockIdx.x & 1) << 8) + threadIdx.x;
  int qy = q / 14, qx = q % 14;

  float acc[4][20];
#pragma unroll
  for (int t = 0; t < 4; ++t)
#pragma unroll
    for (int oc = 0; oc < 20; ++oc) acc[t][oc] = 0.f;

#pragma unroll
  for (int t = 0; t < 4; ++t) {
    int y = 2 * qy + (t >> 1);
    int xx = 2 * qx + (t & 1);
#pragma unroll
    for (int ky = 0; ky < 5; ++ky) {
      int iy = y + ky - 2;
      if (iy < 0 || iy >= 28) continue;    // block-uniform
#pragma unroll
      for (int kx = 0; kx < 5; ++kx) {
        int ix = xx + kx - 2;
        if (ix < 0 || ix >= 28) continue;  // block-uniform
        float v = (float)pois[(iy * 28 + ix) * 512 + b];
#pragma unroll
        for (int oc = 0; oc < 20; ++oc)
          acc[t][oc] += w1[oc * 25 + ky * 5 + kx] * v;
      }
    }
  }

#pragma unroll
  for (int oc = 0; oc < 20; ++oc) {
    float s4[4];
#pragma unroll
    for (int t = 0; t < 4; ++t) {
      int y = 2 * qy + (t >> 1);
      int xx = 2 * qx + (t & 1);
      int idx = (oc * 784 + y * 28 + xx) * 512 + b;
      float m = m1[idx] + acc[t][oc];
      float sp = 0.f;
      if (m > 1.0f) { sp = 1.f; m = 0.f; }
      m1[idx] = m;
      s4[t] = sp;
    }
    float a = 0.25f * (((s4[0] + s4[1]) + s4[2]) + s4[3]);
    int pidx = (oc * 196 + q) * 512 + b;
    float mm = m1s[pidx] + a;
    uint8_t spp = 0;
    if (mm > 0.75f) { spp = 1; mm = 0.f; }
    m1s[pidx] = mm;
    sp1[pidx] = spp;
  }
}

// ---------------------------------------------------------------------------
// conv2 (20->50, 5x5, pad 2, 14x14) + IF fire. Lane = batch, acc[50] regs.
// u8 in (sp1 = 2MB, L2-resident), u8 spike out. Sum order (ic,ky,kx).
// ---------------------------------------------------------------------------
__global__ __launch_bounds__(256) void c2_k(
    const uint8_t* __restrict__ sp1, const float* __restrict__ wT,
    float* __restrict__ m2, uint8_t* __restrict__ s2) {
  int p = blockIdx.x >> 1;
  int b = ((blockIdx.x & 1) << 8) + threadIdx.x;
  int y = p / 14, xx = p % 14;
  float acc[50];
#pragma unroll
  for (int oc = 0; oc < 50; ++oc) acc[oc] = 0.f;
  for (int ic = 0; ic < 20; ++ic) {
#pragma unroll
    for (int ky = 0; ky < 5; ++ky) {
      int iy = y + ky - 2;
      if (iy < 0 || iy >= 14) continue;
#pragma unroll
      for (int kx = 0; kx < 5; ++kx) {
        int ix = xx + kx - 2;
        if (ix < 0 || ix >= 14) continue;
        float v = (float)sp1[(ic * 196 + iy * 14 + ix) * 512 + b];
        const float* wrow = wT + (ic * 25 + ky * 5 + kx) * 50;
#pragma unroll
        for (int oc = 0; oc < 50; ++oc)
          acc[oc] += wrow[oc] * v;
      }
    }
  }
#pragma unroll
  for (int oc = 0; oc < 50; ++oc) {
    int idx = (oc * 196 + p) * 512 + b;
    float m = m2[idx] + acc[oc];
    uint8_t sp = 0;
    if (m > 1.0f) { sp = 1; m = 0.f; }
    m2[idx] = m;
    s2[idx] = sp;
  }
}

// ---------------------------------------------------------------------------
// 2x2 avgpool + IF fire (layer 2), u8 in / u8 out.
// ---------------------------------------------------------------------------
__global__ void p2_k(const uint8_t* __restrict__ s2, float* __restrict__ m2s,
                     uint8_t* __restrict__ sp2) {
  int t = blockIdx.x * blockDim.x + threadIdx.x;
  if (t >= 1254400) return;
  int b = t & 511;
  int r = t >> 9;
  int c = r / 49, qq = r % 49;
  int yo = qq / 7, xo = qq % 7;
  int ibase = (c * 196 + 2 * yo * 14 + 2 * xo) * 512 + b;
  float s00 = (float)s2[ibase];
  float s01 = (float)s2[ibase + 512];
  float s10 = (float)s2[ibase + 14 * 512];
  float s11 = (float)s2[ibase + 14 * 512 + 512];
  float a = 0.25f * (((s00 + s01) + s10) + s11);
  float m = m2s[t] + a;
  uint8_t sp = 0;
  if (m > 0.75f) { sp = 1; m = 0.f; }
  m2s[t] = m;
  sp2[t] = sp;
}

// ---------------------------------------------------------------------------
// fc0 (2450->200) + IF fire + Tf0. ONE neuron per thread, 400 blocks
// (full occupancy) + u8 sp2 (1.25MB -> L2-resident stream). k ascending,
// unroll-10 batched loads -> bit-identical to all passing rounds.
// ---------------------------------------------------------------------------
__global__ __launch_bounds__(256) void fc0_k(
    const uint8_t* __restrict__ sp2, const float* __restrict__ wf0,
    float* __restrict__ mf0, float* __restrict__ Tf0) {
  int n = blockIdx.x >> 1;                        // 0..199 (block-uniform)
  int b = ((blockIdx.x & 1) << 8) + threadIdx.x;  // 0..511
  const float* w0 = wf0 + n * 2450;               // scalar-pipe loads
  float acc = 0.f;
  for (int k0 = 0; k0 < 2450; k0 += 10) {         // 2450 = 245*10
    float v[10];
#pragma unroll
    for (int u = 0; u < 10; ++u)
      v[u] = (float)sp2[(k0 + u) * 512 + b];
#pragma unroll
    for (int u = 0; u < 10; ++u)
      acc += w0[k0 + u] * v[u];
  }
  int idx = n * 512 + b;
  float m = mf0[idx] + acc;
  float sp = 0.f;
  if (m > 1.0f) { sp = 1.f; m = 0.f; }
  mf0[idx] = m;
  Tf0[idx] += sp;
}

// ---------------------------------------------------------------------------
// final: out[b][i] = (Tf0[.][b] . wf1[i][.]) / 1 / 100   (j ascending)
// ---------------------------------------------------------------------------
__global__ void fc1_k(const float* __restrict__ Tf0,
                      const float* __restrict__ wf1,
                      float* __restrict__ out) {
  int idx = blockIdx.x * blockDim.x + threadIdx.x;
  if (idx >= 5120) return;
  int b = idx / 10, i = idx % 10;
  float a = 0.f;
  for (int j = 0; j < 200; ++j) a += Tf0[j * 512 + b] * wf1[i * 200 + j];
  out[idx] = (a / 1.0f) / 100.0f;
}

// ---------------------------------------------------------------------------
extern "C" void kernel_launch(void* const* d_in, const int* in_sizes, int n_in,
                              void* d_out, int out_size, void* d_ws, size_t ws_size,
                              hipStream_t stream) {
  (void)in_sizes; (void)n_in; (void)out_size; (void)ws_size;
  const float* x   = (const float*)d_in[0];
  const float* w1  = (const float*)d_in[1];
  const float* w2  = (const float*)d_in[2];
  const float* wf0 = (const float*)d_in[3];
  const float* wf1 = (const float*)d_in[4];
  float* out = (float*)d_out;
  float* ws  = (float*)d_ws;

  // fp32 state (zeroed once per launch), batch-innermost
  float* m1   = ws;                 // [20*784][512]  = 8,028,160
  float* m1s  = m1   + 8028160;     // [20*196][512]  = 2,007,040
  float* m2   = m1s  + 2007040;     // [50*196][512]  = 5,017,600
  float* m2s  = m2   + 5017600;     // [50*49][512]   = 1,254,400
  float* mf0  = m2s  + 1254400;     // [200][512]     =   102,400
  float* Tf0  = mf0  + 102400;      // [200][512]     =   102,400
  const size_t state_f = 8028160 + 2007040 + 5017600 + 1254400 + 102400 + 102400;
  // fp32 transients
  float* wT   = Tf0  + 102400;      // [500][50]      =    25,000
  uint32_t* keybuf = (uint32_t*)(wT + 25000);       // 256 u32
  // int8 spike transients
  int8_t*  pois = (int8_t*)(keybuf + 256);          // [784][512]    bytes
  uint8_t* sp1  = (uint8_t*)(pois + 401408);        // [20*196][512]
  uint8_t* s2   = sp1 + 2007040;                    // [50*196][512]
  uint8_t* sp2  = s2  + 5017600;                    // [50*49][512]

  hipMemsetAsync(ws, 0, state_f * sizeof(float), stream);

  keys_k<<<1, 128, 0, stream>>>(keybuf);
  wt_k<<<98, 256, 0, stream>>>(w2, wT);

  for (int s = 0; s < STEPS; ++s) {
    pois_k<<<1568, 256, 0, stream>>>(x, keybuf, s, pois);
    c1_k<<<392, 256, 0, stream>>>(pois, w1, m1, m1s, sp1);
    c2_k<<<392, 256, 0, stream>>>(sp1, wT, m2, s2);
    p2_k<<<4900, 256, 0, stream>>>(s2, m2s, sp2);
    fc0_k<<<400, 256, 0, stream>>>(sp2, wf0, mf0, Tf0);
  }
  fc1_k<<<20, 256, 0, stream>>>(Tf0, wf1, out);
}